// Round 1
// baseline (69.185 us; speedup 1.0000x reference)
//
#include <hip/hip_runtime.h>

#define BB 16
#define NN 512
#define DD 64
#define ROWS (BB * NN)   // 8192

// ---------------- Kernel 1: node transforms ----------------
// xl = x @ Wl^T + bl ; xr = x @ Wr^T + br
// axl = att . xl ; axr = att . xr ; pxl = Wf . xl
__global__ __launch_bounds__(256) void k1_transform(
    const float* __restrict__ x,
    const float* __restrict__ Wl, const float* __restrict__ bl,
    const float* __restrict__ Wr, const float* __restrict__ br,
    const float* __restrict__ att, const float* __restrict__ Wf,
    float* __restrict__ xl, float* __restrict__ xr,
    float* __restrict__ axl, float* __restrict__ axr, float* __restrict__ pxl)
{
    __shared__ float xt[64][65];
    __shared__ float red[3][4][64];
    const int tid = threadIdx.x;
    const int r0 = blockIdx.x * 64;

    // stage 64x64 x-tile into LDS (coalesced float4)
    #pragma unroll
    for (int q = 0; q < 4; ++q) {
        int idx = tid + q * 256;          // 0..1023 float4 slots
        int rl = idx >> 4;
        int kc = idx & 15;
        const float4 v = *reinterpret_cast<const float4*>(&x[(size_t)(r0 + rl) * DD + kc * 4]);
        xt[rl][kc * 4 + 0] = v.x;
        xt[rl][kc * 4 + 1] = v.y;
        xt[rl][kc * 4 + 2] = v.z;
        xt[rl][kc * 4 + 3] = v.w;
    }
    __syncthreads();

    const int lane = tid & 63;   // local row
    const int cg   = tid >> 6;   // column group 0..3 (16 cols each)
    const int row  = r0 + lane;

    float accl[16], accr[16];
    #pragma unroll
    for (int cc = 0; cc < 16; ++cc) {
        accl[cc] = bl[cg * 16 + cc];
        accr[cc] = br[cg * 16 + cc];
    }

    #pragma unroll 4
    for (int k = 0; k < DD; ++k) {
        const float xv = xt[lane][k];
        #pragma unroll
        for (int cc = 0; cc < 16; ++cc) {
            accl[cc] = fmaf(xv, Wl[(cg * 16 + cc) * DD + k], accl[cc]);
            accr[cc] = fmaf(xv, Wr[(cg * 16 + cc) * DD + k], accr[cc]);
        }
    }

    // store xl / xr rows (16 consecutive floats per thread)
    #pragma unroll
    for (int q = 0; q < 4; ++q) {
        float4 vl = make_float4(accl[q*4+0], accl[q*4+1], accl[q*4+2], accl[q*4+3]);
        float4 vr = make_float4(accr[q*4+0], accr[q*4+1], accr[q*4+2], accr[q*4+3]);
        *reinterpret_cast<float4*>(&xl[(size_t)row * DD + cg * 16 + q * 4]) = vl;
        *reinterpret_cast<float4*>(&xr[(size_t)row * DD + cg * 16 + q * 4]) = vr;
    }

    // partial dot products with att / Wf
    float p_axl = 0.f, p_axr = 0.f, p_pxl = 0.f;
    #pragma unroll
    for (int cc = 0; cc < 16; ++cc) {
        const float ac = att[cg * 16 + cc];
        const float wc = Wf[cg * 16 + cc];
        p_axl = fmaf(ac, accl[cc], p_axl);
        p_axr = fmaf(ac, accr[cc], p_axr);
        p_pxl = fmaf(wc, accl[cc], p_pxl);
    }
    red[0][cg][lane] = p_axl;
    red[1][cg][lane] = p_axr;
    red[2][cg][lane] = p_pxl;
    __syncthreads();

    if (tid < 64) {
        axl[r0 + tid] = red[0][0][tid] + red[0][1][tid] + red[0][2][tid] + red[0][3][tid];
        axr[r0 + tid] = red[1][0][tid] + red[1][1][tid] + red[1][2][tid] + red[1][3][tid];
        pxl[r0 + tid] = red[2][0][tid] + red[2][1][tid] + red[2][2][tid] + red[2][3][tid];
    }
}

// ---------------- Kernel 2: attention scores + softmax-weighted scalar aggregation ----
// grid: B * (N/16) = 512 blocks, 512 threads each.
// thread owns source j; computes e[i][j] for 16 targets; then per-wave softmax.
__global__ __launch_bounds__(512) void k2_attn(
    const float* __restrict__ xl, const float* __restrict__ xr,
    const float* __restrict__ axl, const float* __restrict__ axr,
    const float* __restrict__ pxl,
    const float* __restrict__ att,
    const float* __restrict__ bias, const float* __restrict__ Wf,
    const float* __restrict__ bf,
    float* __restrict__ out)
{
    __shared__ float e[16][NN];

    const int tid = threadIdx.x;
    const int b     = blockIdx.x >> 5;        // sample
    const int itile = blockIdx.x & 31;        // target tile (16 rows)
    const int i0 = itile * 16;
    const int j = tid;
    const size_t rowj = (size_t)b * NN + j;

    // xl row in registers
    float xlr[64];
    #pragma unroll
    for (int c = 0; c < 16; ++c) {
        const float4 v = *reinterpret_cast<const float4*>(&xl[rowj * DD + c * 4]);
        xlr[c*4+0] = v.x; xlr[c*4+1] = v.y; xlr[c*4+2] = v.z; xlr[c*4+3] = v.w;
    }
    const float axlj = axl[rowj];

    // constant term: bias.Wf + bf (uniform, cheap)
    float cterm = bf[0];
    #pragma unroll 8
    for (int dd = 0; dd < DD; ++dd) cterm = fmaf(bias[dd], Wf[dd], cterm);

    for (int i = 0; i < 16; ++i) {
        const size_t rowi = (size_t)b * NN + i0 + i;
        const float axri = axr[rowi];
        const float* __restrict__ xrp = &xr[rowi * DD];
        float a0 = 0.f, a1 = 0.f, a2 = 0.f, a3 = 0.f;
        #pragma unroll
        for (int d = 0; d < DD; d += 4) {
            const float z0 = xrp[d+0] + xlr[d+0];
            const float z1 = xrp[d+1] + xlr[d+1];
            const float z2 = xrp[d+2] + xlr[d+2];
            const float z3 = xrp[d+3] + xlr[d+3];
            a0 = fmaf(att[d+0], fabsf(z0), a0);
            a1 = fmaf(att[d+1], fabsf(z1), a1);
            a2 = fmaf(att[d+2], fabsf(z2), a2);
            a3 = fmaf(att[d+3], fabsf(z3), a3);
        }
        e[i][j] = 0.6f * (axri + axlj) + 0.4f * ((a0 + a1) + (a2 + a3));
    }
    __syncthreads();

    // softmax + weighted scalar dot; 8 waves x 2 rows
    const int wv = tid >> 6;
    const int lane = tid & 63;

    float pv[8];
    #pragma unroll
    for (int k = 0; k < 8; ++k) pv[k] = pxl[(size_t)b * NN + lane + 64 * k];

    #pragma unroll
    for (int r = 0; r < 2; ++r) {
        const int i = wv * 2 + r;
        float vals[8];
        #pragma unroll
        for (int k = 0; k < 8; ++k) vals[k] = e[i][lane + 64 * k];

        float m = vals[0];
        #pragma unroll
        for (int k = 1; k < 8; ++k) m = fmaxf(m, vals[k]);
        #pragma unroll
        for (int mask = 32; mask >= 1; mask >>= 1)
            m = fmaxf(m, __shfl_xor(m, mask));

        float s = 0.f, sp = 0.f;
        #pragma unroll
        for (int k = 0; k < 8; ++k) {
            const float t = __expf(vals[k] - m);
            s += t;
            sp = fmaf(t, pv[k], sp);
        }
        #pragma unroll
        for (int mask = 32; mask >= 1; mask >>= 1) {
            s  += __shfl_xor(s, mask);
            sp += __shfl_xor(sp, mask);
        }
        if (lane == 0)
            out[(size_t)b * NN + i0 + i] = sp / s + cterm;
    }
}

extern "C" void kernel_launch(void* const* d_in, const int* in_sizes, int n_in,
                              void* d_out, int out_size, void* d_ws, size_t ws_size,
                              hipStream_t stream) {
    const float* x    = (const float*)d_in[0];
    const float* Wl   = (const float*)d_in[1];
    const float* bl   = (const float*)d_in[2];
    const float* Wr   = (const float*)d_in[3];
    const float* br   = (const float*)d_in[4];
    const float* att  = (const float*)d_in[5];
    const float* bias = (const float*)d_in[6];
    const float* Wf   = (const float*)d_in[7];
    const float* bf   = (const float*)d_in[8];
    float* out = (float*)d_out;

    float* ws  = (float*)d_ws;
    float* xl  = ws;                       // ROWS*DD
    float* xr  = xl + (size_t)ROWS * DD;   // ROWS*DD
    float* axl = xr + (size_t)ROWS * DD;   // ROWS
    float* axr = axl + ROWS;               // ROWS
    float* pxl = axr + ROWS;               // ROWS

    k1_transform<<<ROWS / 64, 256, 0, stream>>>(x, Wl, bl, Wr, br, att, Wf,
                                                xl, xr, axl, axr, pxl);
    k2_attn<<<BB * (NN / 16), 512, 0, stream>>>(xl, xr, axl, axr, pxl,
                                                att, bias, Wf, bf, out);
}

// Round 2
// 41.438 us; speedup vs baseline: 1.6696x; 1.6696x over previous
//
#include <hip/hip_runtime.h>
#include <hip/hip_fp16.h>

#define BB 16
#define NN 512
#define DD 64
#define ROWS (BB * NN)   // 8192
#define ITILE 8          // targets per k2 block

static __device__ __forceinline__ __half2 h2bits(unsigned int u) {
    union { unsigned int i; __half2 h; } c; c.i = u; return c.h;
}
static __device__ __forceinline__ unsigned int bits2(__half2 h) {
    union { __half2 h; unsigned int i; } c; c.h = h; return c.i;
}

// ---------------- Kernel 1: node transforms ----------------
// uh[row][32] = packed half2 of (0.4*att_d * xr_row_d)    (target side, lin_r)
// vh[row][32] = packed half2 of (0.4*att_d * xl_row_d)    (source side, lin_l)
// axl = att . xl ; pxl = Wf . xl ; sgnh = packed sign(att) ; cterm = bias.Wf+bf
__global__ __launch_bounds__(256) void k1_transform(
    const float* __restrict__ x,
    const float* __restrict__ Wl, const float* __restrict__ bl,
    const float* __restrict__ Wr, const float* __restrict__ br,
    const float* __restrict__ att, const float* __restrict__ bias,
    const float* __restrict__ Wf, const float* __restrict__ bf,
    unsigned int* __restrict__ uh, unsigned int* __restrict__ vh,
    float* __restrict__ axl, float* __restrict__ pxl,
    unsigned int* __restrict__ sgnh, float* __restrict__ cterm)
{
    __shared__ float xt[64][65];
    __shared__ float red[2][4][64];
    const int tid = threadIdx.x;
    const int r0 = blockIdx.x * 64;

    // stage 64x64 x-tile (coalesced float4)
    #pragma unroll
    for (int q = 0; q < 4; ++q) {
        int idx = tid + q * 256;
        int rl = idx >> 4;
        int kc = idx & 15;
        const float4 v = *reinterpret_cast<const float4*>(&x[(size_t)(r0 + rl) * DD + kc * 4]);
        xt[rl][kc * 4 + 0] = v.x;
        xt[rl][kc * 4 + 1] = v.y;
        xt[rl][kc * 4 + 2] = v.z;
        xt[rl][kc * 4 + 3] = v.w;
    }
    __syncthreads();

    const int lane = tid & 63;   // local row
    const int cg   = tid >> 6;   // column group 0..3 (16 cols)
    const int row  = r0 + lane;

    float accl[16], accr[16];
    #pragma unroll
    for (int cc = 0; cc < 16; ++cc) {
        accl[cc] = bl[cg * 16 + cc];
        accr[cc] = br[cg * 16 + cc];
    }

    #pragma unroll 4
    for (int k = 0; k < DD; ++k) {
        const float xv = xt[lane][k];
        #pragma unroll
        for (int cc = 0; cc < 16; ++cc) {
            accl[cc] = fmaf(xv, Wl[(cg * 16 + cc) * DD + k], accl[cc]);
            accr[cc] = fmaf(xv, Wr[(cg * 16 + cc) * DD + k], accr[cc]);
        }
    }

    // pack att-scaled halves
    unsigned int up[8], vp[8];
    #pragma unroll
    for (int q = 0; q < 8; ++q) {
        const int d0 = cg * 16 + 2 * q;
        const float c0 = 0.4f * att[d0];
        const float c1 = 0.4f * att[d0 + 1];
        up[q] = bits2(__floats2half2_rn(c0 * accr[2 * q], c1 * accr[2 * q + 1]));
        vp[q] = bits2(__floats2half2_rn(c0 * accl[2 * q], c1 * accl[2 * q + 1]));
    }
    *reinterpret_cast<uint4*>(&uh[(size_t)row * 32 + cg * 8 + 0]) = make_uint4(up[0], up[1], up[2], up[3]);
    *reinterpret_cast<uint4*>(&uh[(size_t)row * 32 + cg * 8 + 4]) = make_uint4(up[4], up[5], up[6], up[7]);
    *reinterpret_cast<uint4*>(&vh[(size_t)row * 32 + cg * 8 + 0]) = make_uint4(vp[0], vp[1], vp[2], vp[3]);
    *reinterpret_cast<uint4*>(&vh[(size_t)row * 32 + cg * 8 + 4]) = make_uint4(vp[4], vp[5], vp[6], vp[7]);

    // partial dot products att.xl and Wf.xl
    float p_axl = 0.f, p_pxl = 0.f;
    #pragma unroll
    for (int cc = 0; cc < 16; ++cc) {
        p_axl = fmaf(att[cg * 16 + cc], accl[cc], p_axl);
        p_pxl = fmaf(Wf[cg * 16 + cc],  accl[cc], p_pxl);
    }
    red[0][cg][lane] = p_axl;
    red[1][cg][lane] = p_pxl;
    __syncthreads();

    if (tid < 64) {
        axl[r0 + tid] = red[0][0][tid] + red[0][1][tid] + red[0][2][tid] + red[0][3][tid];
        pxl[r0 + tid] = red[1][0][tid] + red[1][1][tid] + red[1][2][tid] + red[1][3][tid];
    }

    if (blockIdx.x == 0) {
        if (tid < 32) {
            const float s0 = (att[2 * tid]     >= 0.f) ? 1.f : -1.f;
            const float s1 = (att[2 * tid + 1] >= 0.f) ? 1.f : -1.f;
            sgnh[tid] = bits2(__floats2half2_rn(s0, s1));
        }
        if (tid == 0) {
            float ct = bf[0];
            #pragma unroll 8
            for (int d = 0; d < DD; ++d) ct = fmaf(bias[d], Wf[d], ct);
            *cterm = ct;
        }
    }
}

// ---------------- Kernel 2: scores + softmax-weighted scalar aggregation ----
// grid: B * (N/ITILE) = 1024 blocks, 512 threads; thread owns source j.
// e'_ij = 0.6*axl_j + sum_d sgn_d * |u'_id + v'_jd|   (0.6*axr_i cancels in softmax)
__global__ __launch_bounds__(512, 4) void k2_attn(
    const unsigned int* __restrict__ uh, const unsigned int* __restrict__ vh,
    const float* __restrict__ axl, const float* __restrict__ pxl,
    const unsigned int* __restrict__ sgnh, const float* __restrict__ cterm,
    float* __restrict__ out)
{
    __shared__ unsigned int us[ITILE * 32];   // 1 KB: 8 target u'-rows
    __shared__ float e[ITILE][NN];            // 16 KB

    const int tid = threadIdx.x;
    const int b  = blockIdx.x >> 6;           // sample
    const int i0 = (blockIdx.x & 63) * ITILE; // target base

    // stage u'-rows (8 rows x 32 u32)
    if (tid < 64) {
        const int ir = tid >> 3, c = (tid & 7) * 4;
        *reinterpret_cast<uint4*>(&us[ir * 32 + c]) =
            *reinterpret_cast<const uint4*>(&uh[((size_t)(b * NN + i0 + ir)) * 32 + c]);
    }

    const int j = tid;
    const size_t rowj = (size_t)b * NN + j;

    uint4 vv[8];
    #pragma unroll
    for (int q = 0; q < 8; ++q)
        vv[q] = *reinterpret_cast<const uint4*>(&vh[rowj * 32 + q * 4]);

    __half2 sg[32];
    #pragma unroll
    for (int c = 0; c < 32; ++c) sg[c] = h2bits(sgnh[c]);

    const float axlj = 0.6f * axl[rowj];
    __syncthreads();

    #pragma unroll 2
    for (int i = 0; i < ITILE; ++i) {
        __half2 a0 = __float2half2_rn(0.f), a1 = a0, a2 = a0, a3 = a0;
        #pragma unroll
        for (int c = 0; c < 8; ++c) {
            const uint4 uu = *reinterpret_cast<const uint4*>(&us[i * 32 + c * 4]);
            const uint4 vq = vv[c];
            a0 = __hfma2(sg[c * 4 + 0], __habs2(__hadd2(h2bits(uu.x), h2bits(vq.x))), a0);
            a1 = __hfma2(sg[c * 4 + 1], __habs2(__hadd2(h2bits(uu.y), h2bits(vq.y))), a1);
            a2 = __hfma2(sg[c * 4 + 2], __habs2(__hadd2(h2bits(uu.z), h2bits(vq.z))), a2);
            a3 = __hfma2(sg[c * 4 + 3], __habs2(__hadd2(h2bits(uu.w), h2bits(vq.w))), a3);
        }
        const __half2 h = __hadd2(__hadd2(a0, a1), __hadd2(a2, a3));
        e[i][j] = axlj + __low2float(h) + __high2float(h);
    }
    __syncthreads();

    // softmax + weighted scalar dot; wave wv handles target row i = wv
    const int wv = tid >> 6;
    const int lane = tid & 63;

    float pv[8], vals[8];
    #pragma unroll
    for (int k = 0; k < 8; ++k) pv[k] = pxl[(size_t)b * NN + lane + 64 * k];
    #pragma unroll
    for (int k = 0; k < 8; ++k) vals[k] = e[wv][lane + 64 * k];

    float m = vals[0];
    #pragma unroll
    for (int k = 1; k < 8; ++k) m = fmaxf(m, vals[k]);
    #pragma unroll
    for (int mask = 32; mask >= 1; mask >>= 1)
        m = fmaxf(m, __shfl_xor(m, mask));

    float s = 0.f, sp = 0.f;
    #pragma unroll
    for (int k = 0; k < 8; ++k) {
        const float t = __expf(vals[k] - m);
        s += t;
        sp = fmaf(t, pv[k], sp);
    }
    #pragma unroll
    for (int mask = 32; mask >= 1; mask >>= 1) {
        s  += __shfl_xor(s, mask);
        sp += __shfl_xor(sp, mask);
    }
    if (lane == 0)
        out[(size_t)b * NN + i0 + wv] = sp / s + *cterm;
}

extern "C" void kernel_launch(void* const* d_in, const int* in_sizes, int n_in,
                              void* d_out, int out_size, void* d_ws, size_t ws_size,
                              hipStream_t stream) {
    const float* x    = (const float*)d_in[0];
    const float* Wl   = (const float*)d_in[1];
    const float* bl   = (const float*)d_in[2];
    const float* Wr   = (const float*)d_in[3];
    const float* br   = (const float*)d_in[4];
    const float* att  = (const float*)d_in[5];
    const float* bias = (const float*)d_in[6];
    const float* Wf   = (const float*)d_in[7];
    const float* bf   = (const float*)d_in[8];
    float* out = (float*)d_out;

    unsigned char* ws = (unsigned char*)d_ws;
    unsigned int* uh   = (unsigned int*)ws;                 // ROWS*32 u32
    unsigned int* vh   = uh + (size_t)ROWS * 32;            // ROWS*32 u32
    float*        axl  = (float*)(vh + (size_t)ROWS * 32);  // ROWS
    float*        pxl  = axl + ROWS;                        // ROWS
    unsigned int* sgnh = (unsigned int*)(pxl + ROWS);       // 32
    float*        ctp  = (float*)(sgnh + 32);               // 1

    k1_transform<<<ROWS / 64, 256, 0, stream>>>(x, Wl, bl, Wr, br, att, bias, Wf, bf,
                                                uh, vh, axl, pxl, sgnh, ctp);
    k2_attn<<<BB * (NN / ITILE), 512, 0, stream>>>(uh, vh, axl, pxl, sgnh, ctp, out);
}

// Round 3
// 28.730 us; speedup vs baseline: 2.4081x; 1.4423x over previous
//
#include <hip/hip_runtime.h>
#include <hip/hip_fp16.h>

#define BB 16
#define NN 512
#define DD 64
#define ROWS (BB * NN)   // 8192
#define ITILE 8          // targets per k2 block
#define RB 16            // rows per k1 block

static __device__ __forceinline__ __half2 h2bits(unsigned int u) {
    union { unsigned int i; __half2 h; } c; c.i = u; return c.h;
}
static __device__ __forceinline__ unsigned int bits2(__half2 h) {
    union { __half2 h; unsigned int i; } c; c.h = h; return c.i;
}

// ---------------- Kernel 1: node transforms ----------------
// Computes (per row): xl = x@Wl^T+bl, xr = x@Wr^T+br  (fp32, in registers)
// Emits: uh = packed half2(0.4*att_d*xr_d), vh = packed half2(0.4*att_d*xl_d),
//        axl = att.xl, pxl = Wf.xl, sgnh = packed sign(att), cterm = bias.Wf+bf
__global__ __launch_bounds__(256, 4) void k1_transform(
    const float* __restrict__ x,
    const float* __restrict__ Wl, const float* __restrict__ bl,
    const float* __restrict__ Wr, const float* __restrict__ br,
    const float* __restrict__ att, const float* __restrict__ bias,
    const float* __restrict__ Wf, const float* __restrict__ bf,
    unsigned int* __restrict__ uh, unsigned int* __restrict__ vh,
    float* __restrict__ axl, float* __restrict__ pxl,
    unsigned int* __restrict__ sgnh, float* __restrict__ cterm)
{
    __shared__ float wt[64][132];        // W transposed: wt[k][c], c<64 = Wl, c>=64 = Wr
    __shared__ float xs[RB][66];         // x tile
    __shared__ float red[RB][16][2];     // axl/pxl partials

    const int tid = threadIdx.x;
    const int r0 = blockIdx.x * RB;

    // stage W transposed: 2048 float4 chunks; consecutive lanes -> consecutive c
    // (global read is strided/gathered but L2-resident; LDS writes conflict-free)
    #pragma unroll
    for (int t = 0; t < 8; ++t) {
        const int idx = t * 256 + tid;
        const int c   = idx & 127;
        const int k4  = (idx >> 7) * 4;
        const float* src = (c < 64) ? (Wl + c * DD + k4) : (Wr + (c - 64) * DD + k4);
        const float4 v = *reinterpret_cast<const float4*>(src);
        wt[k4 + 0][c] = v.x;
        wt[k4 + 1][c] = v.y;
        wt[k4 + 2][c] = v.z;
        wt[k4 + 3][c] = v.w;
    }
    // stage x tile (coalesced)
    {
        const int row = tid >> 4, q = tid & 15;
        const float4 v = *reinterpret_cast<const float4*>(&x[(size_t)(r0 + row) * DD + q * 4]);
        xs[row][q * 4 + 0] = v.x;
        xs[row][q * 4 + 1] = v.y;
        xs[row][q * 4 + 2] = v.z;
        xs[row][q * 4 + 3] = v.w;
    }
    __syncthreads();

    const int g  = tid & 31;        // col group (4 cols)
    const int rp = tid >> 5;        // row pair 0..7
    const int c0 = g * 4;           // global col in [0,128)
    const int ra = rp * 2, rb = ra + 1;
    const bool isL = (c0 < 64);
    const int d0 = c0 & 63;         // dim index within its matrix

    const float4 bv = *reinterpret_cast<const float4*>((isL ? bl : br) + d0);
    float acc[2][4];
    #pragma unroll
    for (int r = 0; r < 2; ++r) {
        acc[r][0] = bv.x; acc[r][1] = bv.y; acc[r][2] = bv.z; acc[r][3] = bv.w;
    }

    #pragma unroll 4
    for (int k = 0; k < 64; ++k) {
        const float4 w4 = *reinterpret_cast<const float4*>(&wt[k][c0]);
        const float xa = xs[ra][k];
        const float xb = xs[rb][k];
        acc[0][0] = fmaf(xa, w4.x, acc[0][0]);
        acc[0][1] = fmaf(xa, w4.y, acc[0][1]);
        acc[0][2] = fmaf(xa, w4.z, acc[0][2]);
        acc[0][3] = fmaf(xa, w4.w, acc[0][3]);
        acc[1][0] = fmaf(xb, w4.x, acc[1][0]);
        acc[1][1] = fmaf(xb, w4.y, acc[1][1]);
        acc[1][2] = fmaf(xb, w4.z, acc[1][2]);
        acc[1][3] = fmaf(xb, w4.w, acc[1][3]);
    }

    const float4 av = *reinterpret_cast<const float4*>(&att[d0]);

    // partial dots (xl side only)
    if (isL) {
        const float4 wfv = *reinterpret_cast<const float4*>(&Wf[d0]);
        #pragma unroll
        for (int r = 0; r < 2; ++r) {
            const float pa = av.x * acc[r][0] + av.y * acc[r][1] + av.z * acc[r][2] + av.w * acc[r][3];
            const float pp = wfv.x * acc[r][0] + wfv.y * acc[r][1] + wfv.z * acc[r][2] + wfv.w * acc[r][3];
            red[ra + r][g][0] = pa;
            red[ra + r][g][1] = pp;
        }
    }

    // pack att-scaled halves
    unsigned int* const dst = isL ? vh : uh;
    #pragma unroll
    for (int r = 0; r < 2; ++r) {
        uint2 pk;
        pk.x = bits2(__floats2half2_rn(0.4f * av.x * acc[r][0], 0.4f * av.y * acc[r][1]));
        pk.y = bits2(__floats2half2_rn(0.4f * av.z * acc[r][2], 0.4f * av.w * acc[r][3]));
        *reinterpret_cast<uint2*>(&dst[(size_t)(r0 + ra + r) * 32 + (d0 >> 1)]) = pk;
    }
    __syncthreads();

    if (tid < 32) {
        const int row = tid >> 1, which = tid & 1;
        float s = 0.f;
        #pragma unroll
        for (int gg = 0; gg < 16; ++gg) s += red[row][gg][which];
        if (which) pxl[r0 + row] = s;
        else       axl[r0 + row] = s;
    }

    if (blockIdx.x == 0) {
        if (tid < 32) {
            const float s0 = (att[2 * tid]     >= 0.f) ? 1.f : -1.f;
            const float s1 = (att[2 * tid + 1] >= 0.f) ? 1.f : -1.f;
            sgnh[tid] = bits2(__floats2half2_rn(s0, s1));
        }
        if (tid == 0) {
            float ct = bf[0];
            #pragma unroll 8
            for (int d = 0; d < DD; ++d) ct = fmaf(bias[d], Wf[d], ct);
            *cterm = ct;
        }
    }
}

// ---------------- Kernel 2: scores + softmax-weighted scalar aggregation ----
// grid: B * (N/ITILE) = 1024 blocks, 512 threads; thread owns source j.
// e'_ij = 0.6*axl_j + sum_d sgn_d * |u'_id + v'_jd|   (0.6*axr_i cancels in softmax)
__global__ __launch_bounds__(512, 8) void k2_attn(
    const unsigned int* __restrict__ uh, const unsigned int* __restrict__ vh,
    const float* __restrict__ axl, const float* __restrict__ pxl,
    const unsigned int* __restrict__ sgnh, const float* __restrict__ cterm,
    float* __restrict__ out)
{
    __shared__ unsigned int us[ITILE][32];    // 1 KB: target u'-rows
    __shared__ float e[ITILE][NN];            // 16 KB

    const int tid = threadIdx.x;
    const int b  = blockIdx.x >> 6;
    const int i0 = (blockIdx.x & 63) * ITILE;

    if (tid < 64) {
        const int ir = tid >> 3, c4 = (tid & 7) * 4;
        *reinterpret_cast<uint4*>(&us[ir][c4]) =
            *reinterpret_cast<const uint4*>(&uh[((size_t)(b * NN + i0 + ir)) * 32 + c4]);
    }

    const int j = tid;
    const size_t rowj = (size_t)b * NN + j;
    const float axlj = 0.6f * axl[rowj];
    __syncthreads();

    __half2 acc[ITILE];
    #pragma unroll
    for (int i = 0; i < ITILE; ++i) acc[i] = __float2half2_rn(0.f);

    const uint4* const vbase = reinterpret_cast<const uint4*>(&vh[rowj * 32]);
    const uint4* const sbase = reinterpret_cast<const uint4*>(sgnh);

    #pragma unroll 1
    for (int c = 0; c < 4; ++c) {             // 4 chunks x 16 dims
        const uint4 v0 = vbase[c * 2 + 0];
        const uint4 v1 = vbase[c * 2 + 1];
        const uint4 s0 = sbase[c * 2 + 0];
        const uint4 s1 = sbase[c * 2 + 1];
        #pragma unroll
        for (int i = 0; i < ITILE; ++i) {
            const uint4 u0 = *reinterpret_cast<const uint4*>(&us[i][c * 8 + 0]);
            const uint4 u1 = *reinterpret_cast<const uint4*>(&us[i][c * 8 + 4]);
            __half2 a = acc[i];
            a = __hfma2(h2bits(s0.x), __habs2(__hadd2(h2bits(u0.x), h2bits(v0.x))), a);
            a = __hfma2(h2bits(s0.y), __habs2(__hadd2(h2bits(u0.y), h2bits(v0.y))), a);
            a = __hfma2(h2bits(s0.z), __habs2(__hadd2(h2bits(u0.z), h2bits(v0.z))), a);
            a = __hfma2(h2bits(s0.w), __habs2(__hadd2(h2bits(u0.w), h2bits(v0.w))), a);
            a = __hfma2(h2bits(s1.x), __habs2(__hadd2(h2bits(u1.x), h2bits(v1.x))), a);
            a = __hfma2(h2bits(s1.y), __habs2(__hadd2(h2bits(u1.y), h2bits(v1.y))), a);
            a = __hfma2(h2bits(s1.z), __habs2(__hadd2(h2bits(u1.z), h2bits(v1.z))), a);
            a = __hfma2(h2bits(s1.w), __habs2(__hadd2(h2bits(u1.w), h2bits(v1.w))), a);
            acc[i] = a;
        }
    }

    #pragma unroll
    for (int i = 0; i < ITILE; ++i)
        e[i][j] = axlj + __low2float(acc[i]) + __high2float(acc[i]);
    __syncthreads();

    // softmax + weighted scalar dot; wave wv handles target row i = wv
    const int wv = tid >> 6;
    const int lane = tid & 63;

    float pv[8], vals[8];
    #pragma unroll
    for (int k = 0; k < 8; ++k) pv[k] = pxl[(size_t)b * NN + lane + 64 * k];
    #pragma unroll
    for (int k = 0; k < 8; ++k) vals[k] = e[wv][lane + 64 * k];

    float m = vals[0];
    #pragma unroll
    for (int k = 1; k < 8; ++k) m = fmaxf(m, vals[k]);
    #pragma unroll
    for (int mask = 32; mask >= 1; mask >>= 1)
        m = fmaxf(m, __shfl_xor(m, mask));

    float s = 0.f, sp = 0.f;
    #pragma unroll
    for (int k = 0; k < 8; ++k) {
        const float t = __expf(vals[k] - m);
        s += t;
        sp = fmaf(t, pv[k], sp);
    }
    #pragma unroll
    for (int mask = 32; mask >= 1; mask >>= 1) {
        s  += __shfl_xor(s, mask);
        sp += __shfl_xor(sp, mask);
    }
    if (lane == 0)
        out[(size_t)b * NN + i0 + wv] = sp / s + *cterm;
}

extern "C" void kernel_launch(void* const* d_in, const int* in_sizes, int n_in,
                              void* d_out, int out_size, void* d_ws, size_t ws_size,
                              hipStream_t stream) {
    const float* x    = (const float*)d_in[0];
    const float* Wl   = (const float*)d_in[1];
    const float* bl   = (const float*)d_in[2];
    const float* Wr   = (const float*)d_in[3];
    const float* br   = (const float*)d_in[4];
    const float* att  = (const float*)d_in[5];
    const float* bias = (const float*)d_in[6];
    const float* Wf   = (const float*)d_in[7];
    const float* bf   = (const float*)d_in[8];
    float* out = (float*)d_out;

    unsigned char* ws = (unsigned char*)d_ws;
    unsigned int* uh   = (unsigned int*)ws;                 // ROWS*32 u32
    unsigned int* vh   = uh + (size_t)ROWS * 32;            // ROWS*32 u32
    float*        axl  = (float*)(vh + (size_t)ROWS * 32);  // ROWS
    float*        pxl  = axl + ROWS;                        // ROWS
    unsigned int* sgnh = (unsigned int*)(pxl + ROWS);       // 32
    float*        ctp  = (float*)(sgnh + 32);               // 1

    k1_transform<<<ROWS / RB, 256, 0, stream>>>(x, Wl, bl, Wr, br, att, bias, Wf, bf,
                                                uh, vh, axl, pxl, sgnh, ctp);
    k2_attn<<<BB * (NN / ITILE), 512, 0, stream>>>(uh, vh, axl, pxl, sgnh, ctp, out);
}